// Round 3
// baseline (722.308 us; speedup 1.0000x reference)
//
#include <hip/hip_runtime.h>
#include <math.h>

constexpr int N    = 100000;
constexpr int E    = 1600000;
constexpr int DIN  = 256;
constexpr int D    = 128;
constexpr int L    = 4;
constexpr float EPS = 1e-5f;

typedef __attribute__((ext_vector_type(8))) short bf16x8;
typedef __attribute__((ext_vector_type(4))) float f32x4;

__device__ inline ushort f2b(float f) {
    uint u = __float_as_uint(f);
    uint r = u + 0x7fffu + ((u >> 16) & 1u);
    return (ushort)(r >> 16);
}
__device__ inline float b2f(ushort b) { return __uint_as_float(((uint)b) << 16); }

// ---------------- CSR build ----------------

__global__ void k_count(const int* __restrict__ col, int* __restrict__ cnt) {
    int i = blockIdx.x * 256 + threadIdx.x;
    if (i * 2 + 1 < E) {
        int2 cc = ((const int2*)col)[i];
        atomicAdd(&cnt[cc.x], 1);
        atomicAdd(&cnt[cc.y], 1);
    } else if (i * 2 < E) {
        atomicAdd(&cnt[col[i * 2]], 1);
    }
}

__global__ void k_dis(const int* __restrict__ cnt, float* __restrict__ dis) {
    int n = blockIdx.x * 256 + threadIdx.x;
    if (n < N) dis[n] = rsqrtf((float)cnt[n] + 1.0f);   // +1 self-loop
}

__global__ void k_blocksum(const int* __restrict__ cnt, int* __restrict__ bsum) {
    __shared__ int s[256];
    int base = blockIdx.x * 1024;
    int t = threadIdx.x;
    int a = 0;
    for (int j = 0; j < 4; j++) {
        int idx = base + t * 4 + j;
        if (idx < N) a += cnt[idx];
    }
    s[t] = a; __syncthreads();
    for (int off = 128; off > 0; off >>= 1) {
        if (t < off) s[t] += s[t + off];
        __syncthreads();
    }
    if (t == 0) bsum[blockIdx.x] = s[0];
}

// one block, 128 threads: parallel exclusive scan of bsum (nb <= 128)
__global__ void k_scan(int* __restrict__ bsum, int nb) {
    __shared__ int s[128];
    int t = threadIdx.x;
    int v = (t < nb) ? bsum[t] : 0;
    s[t] = v; __syncthreads();
    for (int off = 1; off < 128; off <<= 1) {
        int x = (t >= off) ? s[t - off] : 0;
        __syncthreads();
        s[t] += x;
        __syncthreads();
    }
    if (t < nb) bsum[t] = s[t] - v;   // exclusive
}

__global__ void k_offsets(const int* __restrict__ cnt, const int* __restrict__ bsum,
                          int* __restrict__ offs) {
    __shared__ int ls[256];
    int b = blockIdx.x, t = threadIdx.x;
    int base = b * 1024;
    int v[4]; int s = 0;
    for (int j = 0; j < 4; j++) {
        int idx = base + t * 4 + j;
        v[j] = (idx < N) ? cnt[idx] : 0;
        s += v[j];
    }
    ls[t] = s; __syncthreads();
    for (int off = 1; off < 256; off <<= 1) {
        int x = (t >= off) ? ls[t - off] : 0;
        __syncthreads();
        ls[t] += x;
        __syncthreads();
    }
    int excl = ((t == 0) ? 0 : ls[t - 1]) + bsum[b];
    for (int j = 0; j < 4; j++) {
        int idx = base + t * 4 + j;
        if (idx < N) offs[idx] = excl;
        excl += v[j];
        if (idx == N - 1) offs[N] = excl;
    }
}

// cur[] is a copy of offs[0..N); one packed 8B record per edge -> 1 granule
__global__ void k_scatter(const int* __restrict__ row, const int* __restrict__ col,
                          const float* __restrict__ dis, int* __restrict__ cur,
                          int2* __restrict__ csr) {
    int e = blockIdx.x * 256 + threadIdx.x;
    if (e >= E) return;
    int c = col[e], r = row[e];
    int pos = atomicAdd(&cur[c], 1);
    csr[pos] = make_int2(r, __float_as_int(dis[r] * dis[c]));
}

// ---------------- weight prep (bf16, identity folded) ----------------

__global__ void k_prep_w(const float* __restrict__ lin1_w, const float* __restrict__ w1,
                         const float* __restrict__ w2, float4 betas,
                         ushort* __restrict__ wb0, ushort* __restrict__ wbc) {
    int i = blockIdx.x * 256 + threadIdx.x;
    if (i < D * DIN) wb0[i] = f2b(lin1_w[i]);
    if (i < L * D * 256) {
        int l = i >> 15, r = i & 32767, d = r >> 8, k = r & 255;
        float beta = (l == 0) ? betas.x : (l == 1) ? betas.y : (l == 2) ? betas.z : betas.w;
        float v;
        if (k < 128) v = beta * w1[l * 16384 + k * 128 + d] + ((k == d) ? (1.f - beta) : 0.f);
        else { int kk = k - 128; v = beta * w2[l * 16384 + kk * 128 + d] + ((kk == d) ? (1.f - beta) : 0.f); }
        wbc[l * 32768 + d * 256 + k] = f2b(v);
    }
}

// ---------------- MFMA GEMM kernels (BM=128, BN=128, K=256) ----------------

#define LSWZ(rw, byt) ((rw) * 512 + ((byt) ^ (((rw) & 15) << 4)))

__global__ __launch_bounds__(256) void k_f0_mfma(const float* __restrict__ x,
        const ushort* __restrict__ wb, const float* __restrict__ bias,
        ushort* __restrict__ f_bf, ushort* __restrict__ x0_bf) {
    __shared__ ushort Al[128 * 256];
    __shared__ ushort Bl[128 * 256];
    int t = threadIdx.x;
    int row0 = blockIdx.x * 128;

    #pragma unroll
    for (int i = 0; i < 16; i++) {
        int c = i * 256 + t;
        int cl = c >> 5, sub = c & 31;
        uint4 v = ((const uint4*)wb)[c];
        *(uint4*)((char*)Bl + LSWZ(cl, sub * 16)) = v;
    }
    #pragma unroll
    for (int i = 0; i < 16; i++) {
        int c = i * 256 + t;
        int rw = c >> 5, sub = c & 31;
        int gr = row0 + rw;
        uint4 p = {0, 0, 0, 0};
        if (gr < N) {
            const float4* src = (const float4*)(x + (size_t)gr * 256 + sub * 8);
            float4 lo = src[0], hi = src[1];
            p.x = (uint)f2b(lo.x) | ((uint)f2b(lo.y) << 16);
            p.y = (uint)f2b(lo.z) | ((uint)f2b(lo.w) << 16);
            p.z = (uint)f2b(hi.x) | ((uint)f2b(hi.y) << 16);
            p.w = (uint)f2b(hi.z) | ((uint)f2b(hi.w) << 16);
        }
        *(uint4*)((char*)Al + LSWZ(rw, sub * 16)) = p;
    }
    __syncthreads();

    int wv = t >> 6, lane = t & 63;
    int l16 = lane & 15, g16 = lane >> 4;
    f32x4 acc[2][8];
    #pragma unroll
    for (int m = 0; m < 2; m++)
        #pragma unroll
        for (int n = 0; n < 8; n++) acc[m][n] = f32x4{0.f, 0.f, 0.f, 0.f};

    #pragma unroll
    for (int ks = 0; ks < 8; ks++) {
        int kb = ks * 64 + g16 * 16;
        bf16x8 a[2], b[8];
        #pragma unroll
        for (int m = 0; m < 2; m++) {
            int r = wv * 32 + m * 16 + l16;
            a[m] = *(const bf16x8*)((const char*)Al + LSWZ(r, kb));
        }
        #pragma unroll
        for (int n = 0; n < 8; n++) {
            int cl = n * 16 + l16;
            b[n] = *(const bf16x8*)((const char*)Bl + LSWZ(cl, kb));
        }
        #pragma unroll
        for (int m = 0; m < 2; m++)
            #pragma unroll
            for (int n = 0; n < 8; n++)
                acc[m][n] = __builtin_amdgcn_mfma_f32_16x16x32_bf16(a[m], b[n], acc[m][n], 0, 0, 0);
    }

    float bc[8];
    #pragma unroll
    for (int n = 0; n < 8; n++) bc[n] = bias[n * 16 + l16];
    #pragma unroll
    for (int m = 0; m < 2; m++)
        #pragma unroll
        for (int j = 0; j < 4; j++) {
            int gr = row0 + wv * 32 + m * 16 + g16 * 4 + j;
            if (gr >= N) continue;
            #pragma unroll
            for (int n = 0; n < 8; n++) {
                float r = fmaxf(acc[m][n][j] + bc[n], 0.f);
                size_t o = (size_t)gr * 128 + n * 16 + l16;
                f_bf[o] = f2b(r);
                x0_bf[o] = f2b(0.5f * r);
            }
        }
}

// out = [h|x0] @ wbc_l ; bf16(out) in-place into h_bf; LN stats -> atomicAdd(sr)
__global__ __launch_bounds__(256) void k_combine_mfma(ushort* __restrict__ h_bf,
        const ushort* __restrict__ x0_bf, const ushort* __restrict__ wb,
        float* __restrict__ sr) {
    __shared__ ushort Al[128 * 256];
    __shared__ ushort Bl[128 * 256];
    __shared__ float red1[256];
    __shared__ float red2[256];
    int t = threadIdx.x;
    int row0 = blockIdx.x * 128;

    #pragma unroll
    for (int i = 0; i < 16; i++) {
        int c = i * 256 + t;
        int cl = c >> 5, sub = c & 31;
        uint4 v = ((const uint4*)wb)[c];
        *(uint4*)((char*)Bl + LSWZ(cl, sub * 16)) = v;
    }
    #pragma unroll
    for (int i = 0; i < 16; i++) {
        int c = i * 256 + t;
        int rw = c >> 5, sub = c & 31;
        int gr = row0 + rw;
        uint4 v = {0, 0, 0, 0};
        if (gr < N) {
            const ushort* src = (sub < 16 ? h_bf : x0_bf) + (size_t)gr * 128;
            v = ((const uint4*)src)[sub & 15];
        }
        *(uint4*)((char*)Al + LSWZ(rw, sub * 16)) = v;
    }
    __syncthreads();

    int wv = t >> 6, lane = t & 63;
    int l16 = lane & 15, g16 = lane >> 4;
    f32x4 acc[2][8];
    #pragma unroll
    for (int m = 0; m < 2; m++)
        #pragma unroll
        for (int n = 0; n < 8; n++) acc[m][n] = f32x4{0.f, 0.f, 0.f, 0.f};

    #pragma unroll
    for (int ks = 0; ks < 8; ks++) {
        int kb = ks * 64 + g16 * 16;
        bf16x8 a[2], b[8];
        #pragma unroll
        for (int m = 0; m < 2; m++) {
            int r = wv * 32 + m * 16 + l16;
            a[m] = *(const bf16x8*)((const char*)Al + LSWZ(r, kb));
        }
        #pragma unroll
        for (int n = 0; n < 8; n++) {
            int cl = n * 16 + l16;
            b[n] = *(const bf16x8*)((const char*)Bl + LSWZ(cl, kb));
        }
        #pragma unroll
        for (int m = 0; m < 2; m++)
            #pragma unroll
            for (int n = 0; n < 8; n++)
                acc[m][n] = __builtin_amdgcn_mfma_f32_16x16x32_bf16(a[m], b[n], acc[m][n], 0, 0, 0);
    }

    float sum = 0.f, sq = 0.f;
    #pragma unroll
    for (int m = 0; m < 2; m++)
        #pragma unroll
        for (int n = 0; n < 8; n++)
            #pragma unroll
            for (int j = 0; j < 4; j++) { float v = acc[m][n][j]; sum += v; sq += v * v; }

    #pragma unroll
    for (int m = 0; m < 2; m++)
        #pragma unroll
        for (int j = 0; j < 4; j++) {
            int gr = row0 + wv * 32 + m * 16 + g16 * 4 + j;
            if (gr >= N) continue;
            #pragma unroll
            for (int n = 0; n < 8; n++)
                h_bf[(size_t)gr * 128 + n * 16 + l16] = f2b(acc[m][n][j]);
        }

    red1[t] = sum; red2[t] = sq; __syncthreads();
    for (int off = 128; off > 0; off >>= 1) {
        if (t < off) { red1[t] += red1[t + off]; red2[t] += red2[t + off]; }
        __syncthreads();
    }
    if (t == 0) { atomicAdd(&sr[0], red1[0]); atomicAdd(&sr[1], red2[0]); }
}

// ---------------- aggregation: wave per node, 2 edges per instr, pipelined ----------------

__global__ __launch_bounds__(256) void k_agg(const ushort* __restrict__ f_bf,
        const int* __restrict__ offs, const int2* __restrict__ csr,
        const float* __restrict__ dis, ushort* __restrict__ h_bf) {
    int node = blockIdx.x * 4 + (threadIdx.x >> 6);
    if (node >= N) return;
    int lane = threadIdx.x & 63;
    int half = lane >> 5, c = lane & 31;          // c: uint2 idx -> channels 4c..4c+3
    const uint2* fu = (const uint2*)f_bf;         // row stride 32 uint2
    float dv = dis[node];
    float w0 = (half == 0) ? dv * dv : 0.f;
    uint2 sf = fu[(size_t)node * 32 + c];
    float a0 = w0 * b2f((ushort)(sf.x & 0xffff));
    float a1 = w0 * b2f((ushort)(sf.x >> 16));
    float a2 = w0 * b2f((ushort)(sf.y & 0xffff));
    float a3 = w0 * b2f((ushort)(sf.y >> 16));

    int e = offs[node], end = offs[node + 1];
    int ecur = e + half;
    if (ecur < end) {
        int2 rec0 = csr[ecur];
        int en1 = ecur + 2;
        int2 rec1 = csr[min(en1, end - 1)];       // prefetch next record
        uint2 row0 = fu[(size_t)rec0.x * 32 + c];
        while (en1 < end) {
            int en2 = en1 + 2;
            int2 rec2 = csr[min(en2, end - 1)];   // prefetch rec for next iter
            uint2 row1 = fu[(size_t)rec1.x * 32 + c]; // addr ready (prefetched)
            float val = __int_as_float(rec0.y);
            a0 += val * b2f((ushort)(row0.x & 0xffff));
            a1 += val * b2f((ushort)(row0.x >> 16));
            a2 += val * b2f((ushort)(row0.y & 0xffff));
            a3 += val * b2f((ushort)(row0.y >> 16));
            rec0 = rec1; rec1 = rec2; row0 = row1; en1 = en2;
        }
        float val = __int_as_float(rec0.y);
        a0 += val * b2f((ushort)(row0.x & 0xffff));
        a1 += val * b2f((ushort)(row0.x >> 16));
        a2 += val * b2f((ushort)(row0.y & 0xffff));
        a3 += val * b2f((ushort)(row0.y >> 16));
    }

    a0 += __shfl_xor(a0, 32, 64);
    a1 += __shfl_xor(a1, 32, 64);
    a2 += __shfl_xor(a2, 32, 64);
    a3 += __shfl_xor(a3, 32, 64);
    if (half == 0) {
        uint2 o;
        o.x = (uint)f2b(0.5f * a0) | ((uint)f2b(0.5f * a1) << 16);
        o.y = (uint)f2b(0.5f * a2) | ((uint)f2b(0.5f * a3) << 16);
        ((uint2*)h_bf)[(size_t)node * 32 + c] = o;
    }
}

// ---------------- LN finalize (stats derived from atomically-summed sr) ----------------

template <int LAST>
__global__ void k_ln_relu(const ushort* __restrict__ ob, const float* __restrict__ sr,
                          const float* __restrict__ nw, const float* __restrict__ nb,
                          ushort* __restrict__ f_bf, float* __restrict__ fout) {
    int i = blockIdx.x * 256 + threadIdx.x;   // uint4 index: 8 bf16
    if (i >= N * 16) return;
    const float inv_n = 1.0f / ((float)N * (float)D);
    float m = sr[0] * inv_n;
    float var = fmaxf(sr[1] * inv_n - m * m, 0.f);
    float inv = 1.0f / (sqrtf(var) + EPS);
    uint4 v = ((const uint4*)ob)[i];
    int c = (i & 15) * 8;
    uint vv[4] = {v.x, v.y, v.z, v.w};
    float r[8];
    #pragma unroll
    for (int q = 0; q < 4; q++) {
        float lo = b2f((ushort)(vv[q] & 0xffff));
        float hi = b2f((ushort)(vv[q] >> 16));
        r[2 * q]     = fmaxf((lo - m) * inv * nw[c + 2 * q]     + nb[c + 2 * q], 0.f);
        r[2 * q + 1] = fmaxf((hi - m) * inv * nw[c + 2 * q + 1] + nb[c + 2 * q + 1], 0.f);
    }
    if (LAST) {
        float4 o0 = {r[0], r[1], r[2], r[3]};
        float4 o1 = {r[4], r[5], r[6], r[7]};
        ((float4*)fout)[2 * i] = o0;
        ((float4*)fout)[2 * i + 1] = o1;
    } else {
        uint4 o;
        o.x = (uint)f2b(r[0]) | ((uint)f2b(r[1]) << 16);
        o.y = (uint)f2b(r[2]) | ((uint)f2b(r[3]) << 16);
        o.z = (uint)f2b(r[4]) | ((uint)f2b(r[5]) << 16);
        o.w = (uint)f2b(r[6]) | ((uint)f2b(r[7]) << 16);
        ((uint4*)f_bf)[i] = o;
    }
}

// ---------------- launcher ----------------

extern "C" void kernel_launch(void* const* d_in, const int* in_sizes, int n_in,
                              void* d_out, int out_size, void* d_ws, size_t ws_size,
                              hipStream_t stream) {
    const float* x      = (const float*)d_in[0];
    const int*   ei     = (const int*)d_in[1];
    const float* lin1_w = (const float*)d_in[2];
    const float* lin1_b = (const float*)d_in[3];
    const float* w1     = (const float*)d_in[4];
    const float* w2     = (const float*)d_in[5];
    const float* nw     = (const float*)d_in[6];
    const float* nb     = (const float*)d_in[7];
    const int* row = ei;
    const int* col = ei + E;
    float* fout = (float*)d_out;

    char* ws = (char*)d_ws;
    size_t off0 = 0;
    auto alloc = [&](size_t bytes) -> char* {
        char* p = ws + off0;
        off0 = (off0 + bytes + 255) & ~(size_t)255;
        return p;
    };
    ushort* f_bf    = (ushort*)alloc((size_t)N * D * 2);
    ushort* x0_bf   = (ushort*)alloc((size_t)N * D * 2);
    ushort* h_bf    = (ushort*)alloc((size_t)N * D * 2);
    float*  dis     = (float*) alloc((size_t)N * 4);
    int*    cnt     = (int*)   alloc((size_t)N * 4);
    int*    offs    = (int*)   alloc((size_t)(N + 1) * 4);
    int*    cur     = (int*)   alloc((size_t)N * 4);
    int*    bsum    = (int*)   alloc((size_t)128 * 4);
    int2*   csr     = (int2*)  alloc((size_t)E * 8);
    float*  stats   = (float*) alloc(64);          // 4 layers x {sum, sumsq}
    ushort* wb0     = (ushort*)alloc((size_t)D * DIN * 2);
    ushort* wbc     = (ushort*)alloc((size_t)L * D * 256 * 2);

    hipMemsetAsync(cnt, 0, (size_t)N * 4, stream);
    hipMemsetAsync(stats, 0, 64, stream);

    // CSR build
    k_count<<<(E / 2 + 255) / 256, 256, 0, stream>>>(col, cnt);
    k_dis<<<(N + 255) / 256, 256, 0, stream>>>(cnt, dis);
    int nbk = (N + 1023) / 1024;   // 98
    k_blocksum<<<nbk, 256, 0, stream>>>(cnt, bsum);
    k_scan<<<1, 128, 0, stream>>>(bsum, nbk);
    k_offsets<<<nbk, 256, 0, stream>>>(cnt, bsum, offs);
    hipMemcpyAsync(cur, offs, (size_t)N * 4, hipMemcpyDeviceToDevice, stream);
    k_scatter<<<(E + 255) / 256, 256, 0, stream>>>(row, col, dis, cur, csr);

    // weight prep
    float4 betas;
    betas.x = logf(1.0f / 1.0f + 1.0f);
    betas.y = logf(1.0f / 2.0f + 1.0f);
    betas.z = logf(1.0f / 3.0f + 1.0f);
    betas.w = logf(1.0f / 4.0f + 1.0f);
    k_prep_w<<<(L * D * 256 + 255) / 256, 256, 0, stream>>>(lin1_w, w1, w2, betas, wb0, wbc);

    int GB = (N + 127) / 128;   // 782
    k_f0_mfma<<<GB, 256, 0, stream>>>(x, wb0, lin1_b, f_bf, x0_bf);

    for (int i = 0; i < L; i++) {
        k_agg<<<(N + 3) / 4, 256, 0, stream>>>(f_bf, offs, csr, dis, h_bf);
        k_combine_mfma<<<GB, 256, 0, stream>>>(h_bf, x0_bf, wbc + (size_t)i * D * 256,
                                               stats + 2 * i);
        if (i < L - 1)
            k_ln_relu<0><<<(N * 16 + 255) / 256, 256, 0, stream>>>(h_bf, stats + 2 * i, nw, nb, f_bf, fout);
        else
            k_ln_relu<1><<<(N * 16 + 255) / 256, 256, 0, stream>>>(h_bf, stats + 2 * i, nw, nb, f_bf, fout);
    }
}